// Round 2
// baseline (5114.172 us; speedup 1.0000x reference)
//
#include <hip/hip_runtime.h>

#define Bsz 2
#define Ssz 2048
#define Hsz 2048
#define NHsz 16
#define HDsz 128
#define K3sz 6144
#define Msz 4096

// ---------------- GEMM + bias: C[M][N] = A[M][K] @ W[K][N] + bias[N] ----------------
// 128x128 tile, BK=32, 256 threads, 8x8 micro-tile per thread (split 4+4 cols/rows
// at +64 offset to keep LDS reads at <=2-way bank aliasing).
template<int BM, int BN, int BK>
__global__ __launch_bounds__(256)
void gemm_bias_f32(const float* __restrict__ A, const float* __restrict__ W,
                   const float* __restrict__ bias, float* __restrict__ C,
                   int M, int N, int K) {
  __shared__ float As[BK][BM + 4];   // stored transposed: As[k][m], pad 132
  __shared__ float Bs[BK][BN + 4];
  const int tid = threadIdx.x;
  const int tx = tid & 15;
  const int ty = tid >> 4;
  const int row0 = blockIdx.y * BM;
  const int col0 = blockIdx.x * BN;
  const float* Ab = A + (size_t)row0 * K;
  const float* Wb = W + col0;

  float acc[8][8];
#pragma unroll
  for (int i = 0; i < 8; ++i)
#pragma unroll
    for (int j = 0; j < 8; ++j) acc[i][j] = 0.f;

  for (int k0 = 0; k0 < K; k0 += BK) {
    // A tile: BM x BK, transpose into As[k][m]
#pragma unroll
    for (int i = 0; i < (BM * BK) / (256 * 4); ++i) {
      int f = tid + i * 256;
      int r = f >> 3;       // BK=32 -> 8 float4 per row
      int c4 = f & 7;
      float4 v = *(const float4*)(Ab + (size_t)r * K + k0 + c4 * 4);
      As[c4 * 4 + 0][r] = v.x;
      As[c4 * 4 + 1][r] = v.y;
      As[c4 * 4 + 2][r] = v.z;
      As[c4 * 4 + 3][r] = v.w;
    }
    // B tile: BK x BN, row-major
#pragma unroll
    for (int i = 0; i < (BK * BN) / (256 * 4); ++i) {
      int f = tid + i * 256;
      int r = f >> 5;       // BN=128 -> 32 float4 per row
      int c4 = f & 31;
      *(float4*)&Bs[r][c4 * 4] = *(const float4*)(Wb + (size_t)(k0 + r) * N + c4 * 4);
    }
    __syncthreads();
#pragma unroll
    for (int kk = 0; kk < BK; ++kk) {
      float a[8], bb[8];
      *(float4*)&a[0] = *(const float4*)&As[kk][ty * 4];
      *(float4*)&a[4] = *(const float4*)&As[kk][64 + ty * 4];
      *(float4*)&bb[0] = *(const float4*)&Bs[kk][tx * 4];
      *(float4*)&bb[4] = *(const float4*)&Bs[kk][64 + tx * 4];
#pragma unroll
      for (int i = 0; i < 8; ++i)
#pragma unroll
        for (int j = 0; j < 8; ++j)
          acc[i][j] += a[i] * bb[j];
    }
    __syncthreads();
  }
  // epilogue: bias + store
#pragma unroll
  for (int i = 0; i < 8; ++i) {
    int rloc = (i < 4) ? (ty * 4 + i) : (64 + ty * 4 + i - 4);
    float* Crow = C + (size_t)(row0 + rloc) * N + col0;
#pragma unroll
    for (int jh = 0; jh < 2; ++jh) {
      int cbase = jh * 64 + tx * 4;
      float4 bv = *(const float4*)(bias + col0 + cbase);
      float4 ov;
      ov.x = acc[i][jh * 4 + 0] + bv.x;
      ov.y = acc[i][jh * 4 + 1] + bv.y;
      ov.z = acc[i][jh * 4 + 2] + bv.z;
      ov.w = acc[i][jh * 4 + 3] + bv.w;
      *(float4*)(Crow + cbase) = ov;
    }
  }
}

// ---------------- RoPE + logn + 1/sqrt(HD), in-place on qkv ----------------
// One thread per (b,s,h,d-pair d/d+64); rewrites q and k.
__global__ __launch_bounds__(256)
void rope_logn(float* __restrict__ qkv, const float* __restrict__ cosb,
               const float* __restrict__ sinb, const float* __restrict__ logn) {
  int idx = blockIdx.x * 256 + threadIdx.x;  // B*S*NH*64 = 4,194,304
  int d = idx & 63;
  int h = (idx >> 6) & 15;
  int s = (idx >> 10) & 2047;
  int b = idx >> 21;
  size_t base = ((size_t)(b * Ssz + s)) * K3sz + h * HDsz;
  float c1 = cosb[s * HDsz + d];
  float s1 = sinb[s * HDsz + d];
  float c2 = cosb[s * HDsz + 64 + d];
  float s2 = sinb[s * HDsz + 64 + d];
  float ln = logn[s] * 0.08838834764831845f;  // logn * 1/sqrt(128)
  float q1 = qkv[base + d], q2 = qkv[base + 64 + d];
  float k1 = qkv[base + Hsz + d], k2 = qkv[base + Hsz + 64 + d];
  qkv[base + d]             = (q1 * c1 - q2 * s1) * ln;
  qkv[base + 64 + d]        = (q2 * c2 + q1 * s2) * ln;
  qkv[base + Hsz + d]       = k1 * c1 - k2 * s1;
  qkv[base + Hsz + 64 + d]  = k2 * c2 + k1 * s2;
}

// ---------------- causal flash attention, fp32 ----------------
// block: 256 threads = 64 q-rows x 4 d-quarters; KV tiles of 32 rows in LDS.
// Thread (r,j) holds q[j*32..j*32+31]; partial dot + quad shfl_xor reduce gives
// every thread the full score row -> softmax is lane-local.
__global__ __launch_bounds__(256)
void flash_attn(const float* __restrict__ qkv, float* __restrict__ ctx) {
  // flat layout [j][k][dd] with row stride 1032 so the 4 broadcast addresses
  // per read land in distinct banks
  __shared__ __align__(16) float Ks[4 * 1032];
  __shared__ __align__(16) float Vs[4 * 1032];
  const int t = threadIdx.x;
  const int r = t >> 2;   // 0..63 q row in tile
  const int j = t & 3;    // 0..3 d-quarter
  const int qi = blockIdx.x;
  const int h = blockIdx.y;
  const int b = blockIdx.z;
  const int sq = qi * 64 + r;

  const float* qrow = qkv + ((size_t)(b * Ssz + sq)) * K3sz + h * HDsz + j * 32;
  float q[32];
#pragma unroll
  for (int i = 0; i < 8; ++i)
    *(float4*)&q[i * 4] = *(const float4*)(qrow + i * 4);

  float o[32];
#pragma unroll
  for (int i = 0; i < 32; ++i) o[i] = 0.f;
  float m = -1e30f, l = 0.f;

  const int ntiles = 2 * qi + 2;  // kv rows 0 .. qi*64+63
  for (int kt = 0; kt < ntiles; ++kt) {
    // stage K,V tile (32 x 128 each)
#pragma unroll
    for (int i = 0; i < 4; ++i) {
      int f = t + i * 256;
      int rr = f >> 5;
      int c4 = f & 31;
      int jj = c4 >> 3;
      int d4 = c4 & 7;
      size_t src = ((size_t)(b * Ssz + kt * 32 + rr)) * K3sz + Hsz + h * HDsz + c4 * 4;
      float4 kvv = *(const float4*)(qkv + src);
      float4 vvv = *(const float4*)(qkv + src + Hsz);
      *(float4*)&Ks[jj * 1032 + rr * 32 + d4 * 4] = kvv;
      *(float4*)&Vs[jj * 1032 + rr * 32 + d4 * 4] = vvv;
    }
    __syncthreads();

    // partial scores over this thread's 32 d's
    float sc[32];
    const float* Kb = &Ks[j * 1032];
#pragma unroll
    for (int k = 0; k < 32; ++k) {
      float a0 = 0.f;
#pragma unroll
      for (int dd = 0; dd < 32; ++dd)
        a0 += q[dd] * Kb[k * 32 + dd];
      sc[k] = a0;
    }
    // quad reduce across j (DPP quad-perm)
#pragma unroll
    for (int k = 0; k < 32; ++k) {
      sc[k] += __shfl_xor(sc[k], 1);
      sc[k] += __shfl_xor(sc[k], 2);
    }
    // causal mask (only the two diagonal tiles hit this)
    if (kt * 32 + 31 > sq) {
#pragma unroll
      for (int k = 0; k < 32; ++k)
        if (kt * 32 + k > sq) sc[k] = -1e30f;
    }
    // online softmax (redundant per j, identical values)
    float tm = sc[0];
#pragma unroll
    for (int k = 1; k < 32; ++k) tm = fmaxf(tm, sc[k]);
    float mnew = fmaxf(m, tm);
    float corr = __expf(m - mnew);
    l *= corr;
#pragma unroll
    for (int dd = 0; dd < 32; ++dd) o[dd] *= corr;
    float ls = 0.f;
#pragma unroll
    for (int k = 0; k < 32; ++k) {
      float p = __expf(sc[k] - mnew);
      sc[k] = p;
      ls += p;
    }
    l += ls;
    m = mnew;
    // PV accumulate over this thread's 32 d's
    const float* Vb = &Vs[j * 1032];
#pragma unroll
    for (int k = 0; k < 32; ++k)
#pragma unroll
      for (int dd = 0; dd < 32; ++dd)
        o[dd] += sc[k] * Vb[k * 32 + dd];
    __syncthreads();
  }

  float inv = 1.f / l;
  float* orow = ctx + ((size_t)(b * Ssz + sq)) * Hsz + h * HDsz + j * 32;
#pragma unroll
  for (int i = 0; i < 8; ++i) {
    float4 ov;
    ov.x = o[i * 4 + 0] * inv;
    ov.y = o[i * 4 + 1] * inv;
    ov.z = o[i * 4 + 2] * inv;
    ov.w = o[i * 4 + 3] * inv;
    *(float4*)(orow + i * 4) = ov;
  }
}

extern "C" void kernel_launch(void* const* d_in, const int* in_sizes, int n_in,
                              void* d_out, int out_size, void* d_ws, size_t ws_size,
                              hipStream_t stream) {
  const float* hs   = (const float*)d_in[0];  // (B,S,H)
  const float* cosb = (const float*)d_in[1];  // (1,S,1,HD)
  const float* sinb = (const float*)d_in[2];
  // d_in[3] = attention_mask: pure causal, handled analytically
  const float* logn = (const float*)d_in[4];  // (1,S,1,1)
  const float* Wc   = (const float*)d_in[5];  // (H, 3H)
  const float* bc   = (const float*)d_in[6];
  const float* Wp   = (const float*)d_in[7];  // (H, H)
  const float* bp   = (const float*)d_in[8];
  float* out = (float*)d_out;

  float* qkv = (float*)d_ws;                       // [4096][6144]
  float* ctx = qkv + (size_t)Msz * K3sz;           // [4096][2048]

  // 1) qkv = hs @ Wc + bc
  {
    dim3 g(K3sz / 128, Msz / 128);
    gemm_bias_f32<128, 128, 32><<<g, 256, 0, stream>>>(hs, Wc, bc, qkv, Msz, K3sz, Hsz);
  }
  // 2) RoPE + logn + scale in-place
  {
    int total = Bsz * Ssz * NHsz * 64;  // pairs
    rope_logn<<<total / 256, 256, 0, stream>>>(qkv, cosb, sinb, logn);
  }
  // 3) causal flash attention -> ctx (B,S,H layout)
  {
    dim3 g(Ssz / 64, NHsz, Bsz);
    flash_attn<<<g, 256, 0, stream>>>(qkv, ctx);
  }
  // 4) out = ctx @ Wp + bp
  {
    dim3 g(Hsz / 128, Msz / 128);
    gemm_bias_f32<128, 128, 32><<<g, 256, 0, stream>>>(ctx, Wp, bp, out, Msz, Hsz, Hsz);
  }
}

// Round 4
// 1901.323 us; speedup vs baseline: 2.6898x; 2.6898x over previous
//
#include <hip/hip_runtime.h>

#define Bsz 2
#define Ssz 2048
#define Hsz 2048
#define NHsz 16
#define HDsz 128
#define K3sz 6144
#define Msz 4096

typedef _Float16 f16x8 __attribute__((ext_vector_type(8)));
typedef float f32x4 __attribute__((ext_vector_type(4)));

// ---------------- GEMM + bias: C[M][N] = A[M][K] @ W[K][N] + bias[N] ----------------
// lda = A row stride (qkv-aliased ctx has lda=6144).
template<int BM, int BN, int BK>
__global__ __launch_bounds__(256)
void gemm_bias_f32(const float* __restrict__ A, const float* __restrict__ W,
                   const float* __restrict__ bias, float* __restrict__ C,
                   int M, int N, int K, int lda) {
  __shared__ float As[BK][BM + 4];
  __shared__ float Bs[BK][BN + 4];
  const int tid = threadIdx.x;
  const int tx = tid & 15;
  const int ty = tid >> 4;
  const int row0 = blockIdx.y * BM;
  const int col0 = blockIdx.x * BN;
  const float* Ab = A + (size_t)row0 * lda;
  const float* Wb = W + col0;

  float acc[8][8];
#pragma unroll
  for (int i = 0; i < 8; ++i)
#pragma unroll
    for (int j = 0; j < 8; ++j) acc[i][j] = 0.f;

  for (int k0 = 0; k0 < K; k0 += BK) {
#pragma unroll
    for (int i = 0; i < (BM * BK) / (256 * 4); ++i) {
      int f = tid + i * 256;
      int r = f >> 3;
      int c4 = f & 7;
      float4 v = *(const float4*)(Ab + (size_t)r * lda + k0 + c4 * 4);
      As[c4 * 4 + 0][r] = v.x;
      As[c4 * 4 + 1][r] = v.y;
      As[c4 * 4 + 2][r] = v.z;
      As[c4 * 4 + 3][r] = v.w;
    }
#pragma unroll
    for (int i = 0; i < (BK * BN) / (256 * 4); ++i) {
      int f = tid + i * 256;
      int r = f >> 5;
      int c4 = f & 31;
      *(float4*)&Bs[r][c4 * 4] = *(const float4*)(Wb + (size_t)(k0 + r) * N + c4 * 4);
    }
    __syncthreads();
#pragma unroll
    for (int kk = 0; kk < BK; ++kk) {
      float a[8], bb[8];
      *(float4*)&a[0] = *(const float4*)&As[kk][ty * 4];
      *(float4*)&a[4] = *(const float4*)&As[kk][64 + ty * 4];
      *(float4*)&bb[0] = *(const float4*)&Bs[kk][tx * 4];
      *(float4*)&bb[4] = *(const float4*)&Bs[kk][64 + tx * 4];
#pragma unroll
      for (int i = 0; i < 8; ++i)
#pragma unroll
        for (int j = 0; j < 8; ++j)
          acc[i][j] += a[i] * bb[j];
    }
    __syncthreads();
  }
#pragma unroll
  for (int i = 0; i < 8; ++i) {
    int rloc = (i < 4) ? (ty * 4 + i) : (64 + ty * 4 + i - 4);
    float* Crow = C + (size_t)(row0 + rloc) * N + col0;
#pragma unroll
    for (int jh = 0; jh < 2; ++jh) {
      int cbase = jh * 64 + tx * 4;
      float4 bv = *(const float4*)(bias + col0 + cbase);
      float4 ov;
      ov.x = acc[i][jh * 4 + 0] + bv.x;
      ov.y = acc[i][jh * 4 + 1] + bv.y;
      ov.z = acc[i][jh * 4 + 2] + bv.z;
      ov.w = acc[i][jh * 4 + 3] + bv.w;
      *(float4*)(Crow + cbase) = ov;
    }
  }
}

// ---------------- RoPE: q' fp32 in-place (logn+scale folded), k' fp16 -> Kh head-major ----------------
__global__ __launch_bounds__(256)
void rope_cvt(float* __restrict__ qkv, const float* __restrict__ cosb,
              const float* __restrict__ sinb, const float* __restrict__ logn,
              _Float16* __restrict__ Kh) {
  int idx = blockIdx.x * 256 + threadIdx.x;  // B*S*NH*64
  int d = idx & 63;
  int h = (idx >> 6) & 15;
  int s = (idx >> 10) & 2047;
  int b = idx >> 21;
  size_t base = ((size_t)(b * Ssz + s)) * K3sz + h * HDsz;
  float c1 = cosb[s * HDsz + d];
  float s1 = sinb[s * HDsz + d];
  float c2 = cosb[s * HDsz + 64 + d];
  float s2 = sinb[s * HDsz + 64 + d];
  float ln = logn[s] * 0.08838834764831845f;  // logn * 1/sqrt(128)
  float q1 = qkv[base + d], q2 = qkv[base + 64 + d];
  float k1 = qkv[base + Hsz + d], k2 = qkv[base + Hsz + 64 + d];
  qkv[base + d]      = (q1 * c1 - q2 * s1) * ln;
  qkv[base + 64 + d] = (q2 * c2 + q1 * s2) * ln;
  size_t ko = ((size_t)((b * NHsz + h) * Ssz + s)) * HDsz;
  Kh[ko + d]      = (_Float16)(k1 * c1 - k2 * s1);
  Kh[ko + 64 + d] = (_Float16)(k2 * c2 + k1 * s2);
}

// ---------------- V transpose: qkv v-part fp32 -> Vt fp16 [bh][128d][2048s] ----------------
__global__ __launch_bounds__(256)
void vtrans(const float* __restrict__ qkv, _Float16* __restrict__ Vt) {
  __shared__ _Float16 T[128][72];  // 144B row stride (16B-aligned)
  const int t = threadIdx.x;
  const int s0 = blockIdx.x * 64;
  const int h = blockIdx.y;
  const int b = blockIdx.z;
#pragma unroll
  for (int i = 0; i < 8; ++i) {
    int c = i * 256 + t;
    int rr = c >> 5;
    int c4 = c & 31;
    float4 v = *(const float4*)(qkv + ((size_t)(b * Ssz + s0 + rr)) * K3sz + 2 * Hsz + h * HDsz + c4 * 4);
    T[c4 * 4 + 0][rr] = (_Float16)v.x;
    T[c4 * 4 + 1][rr] = (_Float16)v.y;
    T[c4 * 4 + 2][rr] = (_Float16)v.z;
    T[c4 * 4 + 3][rr] = (_Float16)v.w;
  }
  __syncthreads();
  _Float16* Vg = Vt + (size_t)(b * NHsz + h) * (Ssz * HDsz);
#pragma unroll
  for (int i = 0; i < 4; ++i) {
    int c = i * 256 + t;
    int d = c >> 3;
    int s8 = c & 7;
    *(f16x8*)(Vg + (size_t)d * Ssz + s0 + s8 * 8) = *(const f16x8*)&T[d][s8 * 8];
  }
}

// ---------------- fp16 MFMA causal flash attention ----------------
// 4 waves x 16 q-rows (q-block 64), KV tile 64. mfma_f32_16x16x32_f16.
// A/B frags: lane l -> row/col l&15, k = (l>>4)*8+j (contiguous 8, b128 reads).
// C/D: col = l&15, row = (l>>4)*4 + reg  [m89-verified, dtype-independent].
// ctx written into the q-region of qkv (aliased; proj GEMM reads lda=6144).
__global__ __launch_bounds__(256)
void flash_mfma(float* __restrict__ qkv, const _Float16* __restrict__ Kh,
                const _Float16* __restrict__ Vt) {
  __shared__ _Float16 Ks[64][136];   // 272B stride: odd x 16B -> 8-slot spread
  __shared__ _Float16 Vs[128][72];   // 144B stride
  __shared__ _Float16 Ps[4][16][72]; // per-wave P tile
  const int t = threadIdx.x;
  const int w = t >> 6;
  const int l = t & 63;
  const int lg = l >> 4;   // 0..3
  const int ll = l & 15;
  const int qblk = 31 - (int)blockIdx.x;  // longest-first (LPT)
  const int h = blockIdx.y;
  const int b = blockIdx.z;
  const size_t bh = (size_t)(b * NHsz + h);

  // Q fragments (roped+logn+scale fp32 in qkv), rows qblk*64 + w*16 + ll
  const int qrow_g = qblk * 64 + w * 16 + ll;
  f16x8 qf[4];
  {
    const float* qrow = qkv + ((size_t)(b * Ssz) + qrow_g) * K3sz + h * HDsz;
#pragma unroll
    for (int kds = 0; kds < 4; ++kds) {
      float4 u = *(const float4*)(qrow + kds * 32 + lg * 8);
      float4 v = *(const float4*)(qrow + kds * 32 + lg * 8 + 4);
      f16x8 a;
      a[0] = (_Float16)u.x; a[1] = (_Float16)u.y; a[2] = (_Float16)u.z; a[3] = (_Float16)u.w;
      a[4] = (_Float16)v.x; a[5] = (_Float16)v.y; a[6] = (_Float16)v.z; a[7] = (_Float16)v.w;
      qf[kds] = a;
    }
  }

  f32x4 O[8];
#pragma unroll
  for (int nf = 0; nf < 8; ++nf)
#pragma unroll
    for (int r = 0; r < 4; ++r) O[nf][r] = 0.f;
  float m[4] = {-1e30f, -1e30f, -1e30f, -1e30f};
  float lsum[4] = {0.f, 0.f, 0.f, 0.f};

  const _Float16* Kg = Kh + bh * (size_t)(Ssz * HDsz);
  const _Float16* Vg = Vt + bh * (size_t)(Ssz * HDsz);

  for (int kt = 0; kt <= qblk; ++kt) {
    // stage K (64x128) and V^T (128x64) fp16 tiles
#pragma unroll
    for (int i = 0; i < 4; ++i) {
      int c = i * 256 + t;
      int rr = c >> 4;
      int c8 = c & 15;
      *(f16x8*)&Ks[rr][c8 * 8] = *(const f16x8*)(Kg + (size_t)(kt * 64 + rr) * HDsz + c8 * 8);
    }
#pragma unroll
    for (int i = 0; i < 4; ++i) {
      int c = i * 256 + t;
      int d = c >> 3;
      int s8 = c & 7;
      *(f16x8*)&Vs[d][s8 * 8] = *(const f16x8*)(Vg + (size_t)d * Ssz + kt * 64 + s8 * 8);
    }
    __syncthreads();

    // QK^T: S[kf] (16q x 16k), accumulate over 4 k-dim slices
    f32x4 S[4];
#pragma unroll
    for (int kf = 0; kf < 4; ++kf) {
#pragma unroll
      for (int r = 0; r < 4; ++r) S[kf][r] = 0.f;
#pragma unroll
      for (int kds = 0; kds < 4; ++kds) {
        f16x8 bk = *(const f16x8*)&Ks[kf * 16 + ll][kds * 32 + lg * 8];
        S[kf] = __builtin_amdgcn_mfma_f32_16x16x32_f16(qf[kds], bk, S[kf], 0, 0, 0);
      }
    }
    // causal mask (diagonal tile only)
    if (kt == qblk) {
#pragma unroll
      for (int kf = 0; kf < 4; ++kf) {
        int kcol = kt * 64 + kf * 16 + ll;
#pragma unroll
        for (int r = 0; r < 4; ++r) {
          int qg = qblk * 64 + w * 16 + lg * 4 + r;
          if (kcol > qg) S[kf][r] = -1e30f;
        }
      }
    }
    // online softmax: rows (lg*4+r), k across kf (in-lane) x 16 lanes
#pragma unroll
    for (int r = 0; r < 4; ++r) {
      float v = fmaxf(fmaxf(S[0][r], S[1][r]), fmaxf(S[2][r], S[3][r]));
      v = fmaxf(v, __shfl_xor(v, 1));
      v = fmaxf(v, __shfl_xor(v, 2));
      v = fmaxf(v, __shfl_xor(v, 4));
      v = fmaxf(v, __shfl_xor(v, 8));
      float mn = fmaxf(m[r], v);
      float corr = __expf(m[r] - mn);
      float p0 = __expf(S[0][r] - mn);
      float p1 = __expf(S[1][r] - mn);
      float p2 = __expf(S[2][r] - mn);
      float p3 = __expf(S[3][r] - mn);
      float ps = (p0 + p1) + (p2 + p3);
      ps += __shfl_xor(ps, 1);
      ps += __shfl_xor(ps, 2);
      ps += __shfl_xor(ps, 4);
      ps += __shfl_xor(ps, 8);
      lsum[r] = lsum[r] * corr + ps;
      m[r] = mn;
#pragma unroll
      for (int nf = 0; nf < 8; ++nf) O[nf][r] *= corr;
      Ps[w][lg * 4 + r][0 * 16 + ll] = (_Float16)p0;
      Ps[w][lg * 4 + r][1 * 16 + ll] = (_Float16)p1;
      Ps[w][lg * 4 + r][2 * 16 + ll] = (_Float16)p2;
      Ps[w][lg * 4 + r][3 * 16 + ll] = (_Float16)p3;
    }
    // PV: O (16q x 128d) += P (16x64) @ V (64x128)
    f16x8 pa0 = *(const f16x8*)&Ps[w][ll][lg * 8];
    f16x8 pa1 = *(const f16x8*)&Ps[w][ll][32 + lg * 8];
#pragma unroll
    for (int nf = 0; nf < 8; ++nf) {
      f16x8 vb0 = *(const f16x8*)&Vs[nf * 16 + ll][lg * 8];
      f16x8 vb1 = *(const f16x8*)&Vs[nf * 16 + ll][32 + lg * 8];
      O[nf] = __builtin_amdgcn_mfma_f32_16x16x32_f16(pa0, vb0, O[nf], 0, 0, 0);
      O[nf] = __builtin_amdgcn_mfma_f32_16x16x32_f16(pa1, vb1, O[nf], 0, 0, 0);
    }
    __syncthreads();
  }

  // write ctx into q-region of qkv (same rows/cols this block owns)
#pragma unroll
  for (int r = 0; r < 4; ++r) {
    float inv = 1.f / lsum[r];
    float* crow = qkv + ((size_t)(b * Ssz) + qblk * 64 + w * 16 + lg * 4 + r) * K3sz + h * HDsz;
#pragma unroll
    for (int nf = 0; nf < 8; ++nf)
      crow[nf * 16 + ll] = O[nf][r] * inv;
  }
}

extern "C" void kernel_launch(void* const* d_in, const int* in_sizes, int n_in,
                              void* d_out, int out_size, void* d_ws, size_t ws_size,
                              hipStream_t stream) {
  const float* hs   = (const float*)d_in[0];
  const float* cosb = (const float*)d_in[1];
  const float* sinb = (const float*)d_in[2];
  // d_in[3] = attention_mask: pure causal, handled analytically
  const float* logn = (const float*)d_in[4];
  const float* Wc   = (const float*)d_in[5];
  const float* bc   = (const float*)d_in[6];
  const float* Wp   = (const float*)d_in[7];
  const float* bp   = (const float*)d_in[8];
  float* out = (float*)d_out;

  float* qkv = (float*)d_ws;                                   // 4096x6144 f32 (100.7 MB)
  _Float16* Kh = (_Float16*)(qkv + (size_t)Msz * K3sz);        // [bh][s][d] fp16 (16.8 MB)
  _Float16* Vt = Kh + (size_t)Bsz * NHsz * Ssz * HDsz;         // [bh][d][s] fp16 (16.8 MB)
  // total = 128 MiB exactly (same footprint as the verified round-2 kernel)

  // 1) qkv = hs @ Wc + bc
  {
    dim3 g(K3sz / 128, Msz / 128);
    gemm_bias_f32<128, 128, 32><<<g, 256, 0, stream>>>(hs, Wc, bc, qkv, Msz, K3sz, Hsz, Hsz);
  }
  // 2) RoPE: q fp32 in-place (+logn+scale), k -> Kh fp16 head-major
  {
    int total = Bsz * Ssz * NHsz * 64;
    rope_cvt<<<total / 256, 256, 0, stream>>>(qkv, cosb, sinb, logn, Kh);
  }
  // 3) V -> Vt fp16 [bh][d][s]
  {
    dim3 g(Ssz / 64, NHsz, Bsz);
    vtrans<<<g, 256, 0, stream>>>(qkv, Vt);
  }
  // 4) fp16 MFMA causal flash attention; ctx aliased into qkv q-region
  {
    dim3 g(Ssz / 64, NHsz, Bsz);
    flash_mfma<<<g, 256, 0, stream>>>(qkv, Kh, Vt);
  }
  // 5) out = ctx @ Wp + bp   (A = qkv q-region, lda = 6144)
  {
    dim3 g(Hsz / 128, Msz / 128);
    gemm_bias_f32<128, 128, 32><<<g, 256, 0, stream>>>(qkv, Wp, bp, out, Msz, Hsz, Hsz, K3sz);
  }
}

// Round 5
// 533.445 us; speedup vs baseline: 9.5871x; 3.5642x over previous
//
#include <hip/hip_runtime.h>

#define Bsz 2
#define Ssz 2048
#define Hsz 2048
#define NHsz 16
#define HDsz 128
#define K3sz 6144
#define Msz 4096

typedef _Float16 f16x8 __attribute__((ext_vector_type(8)));
typedef float f32x4 __attribute__((ext_vector_type(4)));

// ---------------- fp32 -> fp16 bulk convert ----------------
__global__ __launch_bounds__(256)
void cvt_f32_f16(const float* __restrict__ in, _Float16* __restrict__ out) {
  size_t i = ((size_t)blockIdx.x * 256 + threadIdx.x) * 8;
  float4 a = *(const float4*)(in + i);
  float4 b = *(const float4*)(in + i + 4);
  f16x8 v;
  v[0] = (_Float16)a.x; v[1] = (_Float16)a.y; v[2] = (_Float16)a.z; v[3] = (_Float16)a.w;
  v[4] = (_Float16)b.x; v[5] = (_Float16)b.y; v[6] = (_Float16)b.z; v[7] = (_Float16)b.w;
  *(f16x8*)(out + i) = v;
}

// ---------------- W [K][N] fp32 -> WT [N][K] fp16 (64x64 tiles via LDS) ----------------
__global__ __launch_bounds__(256)
void wtrans(const float* __restrict__ W, _Float16* __restrict__ WT, int N, int K) {
  __shared__ _Float16 T[64][72];   // [n][k], 144B rows
  const int t = threadIdx.x;
  const int n0 = blockIdx.x * 64, k0 = blockIdx.y * 64;
#pragma unroll
  for (int i = 0; i < 4; ++i) {
    int c = i * 256 + t;          // 64 k-rows x 16 float4
    int rr = c >> 4, c4 = c & 15;
    float4 v = *(const float4*)(W + (size_t)(k0 + rr) * N + n0 + c4 * 4);
    T[c4 * 4 + 0][rr] = (_Float16)v.x;
    T[c4 * 4 + 1][rr] = (_Float16)v.y;
    T[c4 * 4 + 2][rr] = (_Float16)v.z;
    T[c4 * 4 + 3][rr] = (_Float16)v.w;
  }
  __syncthreads();
#pragma unroll
  for (int i = 0; i < 2; ++i) {
    int c = i * 256 + t;          // 64 n-rows x 8 f16x8
    int nn = c >> 3, k8 = c & 7;
    *(f16x8*)(WT + (size_t)(n0 + nn) * K + k0 + k8 * 8) = *(const f16x8*)&T[nn][k8 * 8];
  }
}

// ---------------- fp16 MFMA GEMM: C[M][N] = A[M][K] @ WT[N][K]^T + bias ----------------
// 128x128 tile, BK=64, 4 waves (2x2, 64x64 each), mfma_f32_16x16x32_f16.
// Fragment pattern identical to the HW-verified flash_mfma mapping (round 4).
// LDS rows padded to 72 halfwords (144B): even bank spread on b128 reads/writes.
template<typename CT>
__global__ __launch_bounds__(256)
void gemm_f16(const _Float16* __restrict__ A, int lda,
              const _Float16* __restrict__ BT,
              const float* __restrict__ bias,
              CT* __restrict__ C, int ldc, int K) {
  __shared__ _Float16 As[128][72];
  __shared__ _Float16 Bs[128][72];
  const int t = threadIdx.x;
  const int w = t >> 6, l = t & 63, lg = l >> 4, ll = l & 15;
  const int wr = w >> 1, wc = w & 1;
  const int m0 = blockIdx.y * 128, c0 = blockIdx.x * 128;

  f32x4 acc[4][4];
#pragma unroll
  for (int mf = 0; mf < 4; ++mf)
#pragma unroll
    for (int nf = 0; nf < 4; ++nf)
#pragma unroll
      for (int r = 0; r < 4; ++r) acc[mf][nf][r] = 0.f;

  for (int k0 = 0; k0 < K; k0 += 64) {
#pragma unroll
    for (int i = 0; i < 4; ++i) {
      int c = i * 256 + t;        // 128 rows x 8 f16x8
      int row = c >> 3, c8 = c & 7;
      *(f16x8*)&As[row][c8 * 8] = *(const f16x8*)(A  + (size_t)(m0 + row) * lda + k0 + c8 * 8);
      *(f16x8*)&Bs[row][c8 * 8] = *(const f16x8*)(BT + (size_t)(c0 + row) * K   + k0 + c8 * 8);
    }
    __syncthreads();
#pragma unroll
    for (int ks = 0; ks < 2; ++ks) {
      f16x8 af[4], bf[4];
#pragma unroll
      for (int x = 0; x < 4; ++x) {
        af[x] = *(const f16x8*)&As[wr * 64 + x * 16 + ll][ks * 32 + lg * 8];
        bf[x] = *(const f16x8*)&Bs[wc * 64 + x * 16 + ll][ks * 32 + lg * 8];
      }
#pragma unroll
      for (int mf = 0; mf < 4; ++mf)
#pragma unroll
        for (int nf = 0; nf < 4; ++nf)
          acc[mf][nf] = __builtin_amdgcn_mfma_f32_16x16x32_f16(af[mf], bf[nf], acc[mf][nf], 0, 0, 0);
    }
    __syncthreads();
  }
#pragma unroll
  for (int mf = 0; mf < 4; ++mf)
#pragma unroll
    for (int nf = 0; nf < 4; ++nf) {
      int col = c0 + wc * 64 + nf * 16 + ll;
      float bv = bias[col];
#pragma unroll
      for (int r = 0; r < 4; ++r) {
        int row = m0 + wr * 64 + mf * 16 + lg * 4 + r;
        C[(size_t)row * ldc + col] = (CT)(acc[mf][nf][r] + bv);
      }
    }
}

// ---------------- RoPE on fp16 qkv: q' in-place (logn+scale folded), k' -> Kh ----------------
__global__ __launch_bounds__(256)
void rope_cvt(_Float16* __restrict__ qkv, const float* __restrict__ cosb,
              const float* __restrict__ sinb, const float* __restrict__ logn,
              _Float16* __restrict__ Kh) {
  int idx = blockIdx.x * 256 + threadIdx.x;  // B*S*NH*64
  int d = idx & 63;
  int h = (idx >> 6) & 15;
  int s = (idx >> 10) & 2047;
  int b = idx >> 21;
  size_t base = ((size_t)(b * Ssz + s)) * K3sz + h * HDsz;
  float c1 = cosb[s * HDsz + d];
  float s1 = sinb[s * HDsz + d];
  float c2 = cosb[s * HDsz + 64 + d];
  float s2 = sinb[s * HDsz + 64 + d];
  float ln = logn[s] * 0.08838834764831845f;  // logn * 1/sqrt(128)
  float q1 = (float)qkv[base + d], q2 = (float)qkv[base + 64 + d];
  float k1 = (float)qkv[base + Hsz + d], k2 = (float)qkv[base + Hsz + 64 + d];
  qkv[base + d]      = (_Float16)((q1 * c1 - q2 * s1) * ln);
  qkv[base + 64 + d] = (_Float16)((q2 * c2 + q1 * s2) * ln);
  size_t ko = ((size_t)((b * NHsz + h) * Ssz + s)) * HDsz;
  Kh[ko + d]      = (_Float16)(k1 * c1 - k2 * s1);
  Kh[ko + 64 + d] = (_Float16)(k2 * c2 + k1 * s2);
}

// ---------------- V transpose: qkv v-third fp16 -> Vt [bh][128d][2048s] ----------------
__global__ __launch_bounds__(256)
void vtrans(const _Float16* __restrict__ qkv, _Float16* __restrict__ Vt) {
  __shared__ _Float16 T[128][72];
  const int t = threadIdx.x;
  const int s0 = blockIdx.x * 64;
  const int h = blockIdx.y;
  const int b = blockIdx.z;
#pragma unroll
  for (int i = 0; i < 4; ++i) {
    int c = i * 256 + t;          // 64 s-rows x 16 f16x8
    int rr = c >> 4, c8 = c & 15;
    f16x8 v = *(const f16x8*)(qkv + ((size_t)(b * Ssz + s0 + rr)) * K3sz + 2 * Hsz + h * HDsz + c8 * 8);
#pragma unroll
    for (int j = 0; j < 8; ++j) T[c8 * 8 + j][rr] = v[j];
  }
  __syncthreads();
  _Float16* Vg = Vt + (size_t)(b * NHsz + h) * (Ssz * HDsz);
#pragma unroll
  for (int i = 0; i < 4; ++i) {
    int c = i * 256 + t;          // 128 d-rows x 8 f16x8
    int d = c >> 3, s8 = c & 7;
    *(f16x8*)(Vg + (size_t)d * Ssz + s0 + s8 * 8) = *(const f16x8*)&T[d][s8 * 8];
  }
}

// ---------------- fp16 MFMA causal flash attention (round-4 verified structure) ----------------
__global__ __launch_bounds__(256)
void flash_mfma(_Float16* __restrict__ qkv, const _Float16* __restrict__ Kh,
                const _Float16* __restrict__ Vt) {
  __shared__ _Float16 Ks[64][136];
  __shared__ _Float16 Vs[128][72];
  __shared__ _Float16 Ps[4][16][72];
  const int t = threadIdx.x;
  const int w = t >> 6;
  const int l = t & 63;
  const int lg = l >> 4;
  const int ll = l & 15;
  const int qblk = 31 - (int)blockIdx.x;  // longest-first (LPT)
  const int h = blockIdx.y;
  const int b = blockIdx.z;
  const size_t bh = (size_t)(b * NHsz + h);

  const int qrow_g = qblk * 64 + w * 16 + ll;
  f16x8 qf[4];
  {
    const _Float16* qrow = qkv + ((size_t)(b * Ssz) + qrow_g) * K3sz + h * HDsz;
#pragma unroll
    for (int kds = 0; kds < 4; ++kds)
      qf[kds] = *(const f16x8*)(qrow + kds * 32 + lg * 8);
  }

  f32x4 O[8];
#pragma unroll
  for (int nf = 0; nf < 8; ++nf)
#pragma unroll
    for (int r = 0; r < 4; ++r) O[nf][r] = 0.f;
  float m[4] = {-1e30f, -1e30f, -1e30f, -1e30f};
  float lsum[4] = {0.f, 0.f, 0.f, 0.f};

  const _Float16* Kg = Kh + bh * (size_t)(Ssz * HDsz);
  const _Float16* Vg = Vt + bh * (size_t)(Ssz * HDsz);

  for (int kt = 0; kt <= qblk; ++kt) {
#pragma unroll
    for (int i = 0; i < 4; ++i) {
      int c = i * 256 + t;
      int rr = c >> 4, c8 = c & 15;
      *(f16x8*)&Ks[rr][c8 * 8] = *(const f16x8*)(Kg + (size_t)(kt * 64 + rr) * HDsz + c8 * 8);
    }
#pragma unroll
    for (int i = 0; i < 4; ++i) {
      int c = i * 256 + t;
      int d = c >> 3, s8 = c & 7;
      *(f16x8*)&Vs[d][s8 * 8] = *(const f16x8*)(Vg + (size_t)d * Ssz + kt * 64 + s8 * 8);
    }
    __syncthreads();

    f32x4 S[4];
#pragma unroll
    for (int kf = 0; kf < 4; ++kf) {
#pragma unroll
      for (int r = 0; r < 4; ++r) S[kf][r] = 0.f;
#pragma unroll
      for (int kds = 0; kds < 4; ++kds) {
        f16x8 bk = *(const f16x8*)&Ks[kf * 16 + ll][kds * 32 + lg * 8];
        S[kf] = __builtin_amdgcn_mfma_f32_16x16x32_f16(qf[kds], bk, S[kf], 0, 0, 0);
      }
    }
    if (kt == qblk) {
#pragma unroll
      for (int kf = 0; kf < 4; ++kf) {
        int kcol = kt * 64 + kf * 16 + ll;
#pragma unroll
        for (int r = 0; r < 4; ++r) {
          int qg = qblk * 64 + w * 16 + lg * 4 + r;
          if (kcol > qg) S[kf][r] = -1e30f;
        }
      }
    }
#pragma unroll
    for (int r = 0; r < 4; ++r) {
      float v = fmaxf(fmaxf(S[0][r], S[1][r]), fmaxf(S[2][r], S[3][r]));
      v = fmaxf(v, __shfl_xor(v, 1));
      v = fmaxf(v, __shfl_xor(v, 2));
      v = fmaxf(v, __shfl_xor(v, 4));
      v = fmaxf(v, __shfl_xor(v, 8));
      float mn = fmaxf(m[r], v);
      float corr = __expf(m[r] - mn);
      float p0 = __expf(S[0][r] - mn);
      float p1 = __expf(S[1][r] - mn);
      float p2 = __expf(S[2][r] - mn);
      float p3 = __expf(S[3][r] - mn);
      float ps = (p0 + p1) + (p2 + p3);
      ps += __shfl_xor(ps, 1);
      ps += __shfl_xor(ps, 2);
      ps += __shfl_xor(ps, 4);
      ps += __shfl_xor(ps, 8);
      lsum[r] = lsum[r] * corr + ps;
      m[r] = mn;
#pragma unroll
      for (int nf = 0; nf < 8; ++nf) O[nf][r] *= corr;
      Ps[w][lg * 4 + r][0 * 16 + ll] = (_Float16)p0;
      Ps[w][lg * 4 + r][1 * 16 + ll] = (_Float16)p1;
      Ps[w][lg * 4 + r][2 * 16 + ll] = (_Float16)p2;
      Ps[w][lg * 4 + r][3 * 16 + ll] = (_Float16)p3;
    }
    f16x8 pa0 = *(const f16x8*)&Ps[w][ll][lg * 8];
    f16x8 pa1 = *(const f16x8*)&Ps[w][ll][32 + lg * 8];
#pragma unroll
    for (int nf = 0; nf < 8; ++nf) {
      f16x8 vb0 = *(const f16x8*)&Vs[nf * 16 + ll][lg * 8];
      f16x8 vb1 = *(const f16x8*)&Vs[nf * 16 + ll][32 + lg * 8];
      O[nf] = __builtin_amdgcn_mfma_f32_16x16x32_f16(pa0, vb0, O[nf], 0, 0, 0);
      O[nf] = __builtin_amdgcn_mfma_f32_16x16x32_f16(pa1, vb1, O[nf], 0, 0, 0);
    }
    __syncthreads();
  }

  // ctx (fp16) into the q-region of qkv — own rows only, race-free
#pragma unroll
  for (int r = 0; r < 4; ++r) {
    float inv = 1.f / lsum[r];
    _Float16* crow = qkv + ((size_t)(b * Ssz) + qblk * 64 + w * 16 + lg * 4 + r) * K3sz + h * HDsz;
#pragma unroll
    for (int nf = 0; nf < 8; ++nf)
      crow[nf * 16 + ll] = (_Float16)(O[nf][r] * inv);
  }
}

extern "C" void kernel_launch(void* const* d_in, const int* in_sizes, int n_in,
                              void* d_out, int out_size, void* d_ws, size_t ws_size,
                              hipStream_t stream) {
  const float* hs   = (const float*)d_in[0];
  const float* cosb = (const float*)d_in[1];
  const float* sinb = (const float*)d_in[2];
  // d_in[3] = attention_mask: pure causal, handled analytically
  const float* logn = (const float*)d_in[4];
  const float* Wc   = (const float*)d_in[5];
  const float* bc   = (const float*)d_in[6];
  const float* Wp   = (const float*)d_in[7];
  const float* bp   = (const float*)d_in[8];
  float* out = (float*)d_out;

  // workspace layout: exactly 128 MiB (footprint proven in rounds 2/4)
  _Float16* qkv  = (_Float16*)d_ws;                      // [4096][6144]  50.3 MB
  _Float16* hsF  = qkv  + (size_t)Msz * K3sz;            // [4096][2048]  16.8 MB
  _Float16* WcT  = hsF  + (size_t)Msz * Hsz;             // [6144][2048]  25.2 MB
  _Float16* WpT  = WcT  + (size_t)K3sz * Hsz;            // [2048][2048]   8.4 MB
  _Float16* Kh   = WpT  + (size_t)Hsz * Hsz;             // [bh][s][d]    16.8 MB
  _Float16* Vt   = Kh   + (size_t)Bsz * NHsz * Ssz * HDsz; // [bh][d][s]  16.8 MB

  // 0) precision prepasses
  cvt_f32_f16<<<(Msz * Hsz) / (256 * 8), 256, 0, stream>>>(hs, hsF);
  { dim3 g(K3sz / 64, Hsz / 64); wtrans<<<g, 256, 0, stream>>>(Wc, WcT, K3sz, Hsz); }
  { dim3 g(Hsz / 64, Hsz / 64);  wtrans<<<g, 256, 0, stream>>>(Wp, WpT, Hsz, Hsz); }

  // 1) qkv = hs @ Wc + bc  (fp16 MFMA)
  {
    dim3 g(K3sz / 128, Msz / 128);
    gemm_f16<_Float16><<<g, 256, 0, stream>>>(hsF, Hsz, WcT, bc, qkv, K3sz, Hsz);
  }
  // 2) RoPE: q in-place (+logn+scale), k -> Kh
  rope_cvt<<<(Bsz * Ssz * NHsz * 64) / 256, 256, 0, stream>>>(qkv, cosb, sinb, logn, Kh);
  // 3) V -> Vt [bh][d][s]
  {
    dim3 g(Ssz / 64, NHsz, Bsz);
    vtrans<<<g, 256, 0, stream>>>(qkv, Vt);
  }
  // 4) causal flash attention; ctx fp16 aliased into qkv q-region
  {
    dim3 g(Ssz / 64, NHsz, Bsz);
    flash_mfma<<<g, 256, 0, stream>>>(qkv, Kh, Vt);
  }
  // 5) out = ctx @ Wp + bp  (fp16 MFMA, fp32 out)
  {
    dim3 g(Hsz / 128, Msz / 128);
    gemm_f16<float><<<g, 256, 0, stream>>>(qkv, K3sz, WpT, bp, out, Hsz, Hsz);
  }
}

// Round 6
// 495.835 us; speedup vs baseline: 10.3143x; 1.0759x over previous
//
#include <hip/hip_runtime.h>

#define Bsz 2
#define Ssz 2048
#define Hsz 2048
#define NHsz 16
#define HDsz 128
#define K3sz 6144
#define Msz 4096

typedef _Float16 f16x8 __attribute__((ext_vector_type(8)));
typedef float f32x4 __attribute__((ext_vector_type(4)));

typedef __attribute__((address_space(3))) void lds_void;
typedef __attribute__((address_space(1))) void glob_void;
__device__ __forceinline__ void async_copy16(void* lds, const void* g) {
  __builtin_amdgcn_global_load_lds((const glob_void*)g, (lds_void*)lds, 16, 0, 0);
}

__global__ __launch_bounds__(256)
void cvt_f32_f16(const float* __restrict__ in, _Float16* __restrict__ out) {
  size_t i = ((size_t)blockIdx.x * 256 + threadIdx.x) * 8;
  float4 a = *(const float4*)(in + i);
  float4 b = *(const float4*)(in + i + 4);
  f16x8 v;
  v[0] = (_Float16)a.x; v[1] = (_Float16)a.y; v[2] = (_Float16)a.z; v[3] = (_Float16)a.w;
  v[4] = (_Float16)b.x; v[5] = (_Float16)b.y; v[6] = (_Float16)b.z; v[7] = (_Float16)b.w;
  *(f16x8*)(out + i) = v;
}

__global__ __launch_bounds__(256)
void wtrans(const float* __restrict__ W, _Float16* __restrict__ WT, int N, int K) {
  __shared__ _Float16 T[64][72];
  const int t = threadIdx.x;
  const int n0 = blockIdx.x * 64, k0 = blockIdx.y * 64;
#pragma unroll
  for (int i = 0; i < 4; ++i) {
    int c = i * 256 + t;
    int rr = c >> 4, c4 = c & 15;
    float4 v = *(const float4*)(W + (size_t)(k0 + rr) * N + n0 + c4 * 4);
    T[c4 * 4 + 0][rr] = (_Float16)v.x;
    T[c4 * 4 + 1][rr] = (_Float16)v.y;
    T[c4 * 4 + 2][rr] = (_Float16)v.z;
    T[c4 * 4 + 3][rr] = (_Float16)v.w;
  }
  __syncthreads();
#pragma unroll
  for (int i = 0; i < 2; ++i) {
    int c = i * 256 + t;
    int nn = c >> 3, k8 = c & 7;
    *(f16x8*)(WT + (size_t)(n0 + nn) * K + k0 + k8 * 8) = *(const f16x8*)&T[nn][k8 * 8];
  }
}

// fp16 MFMA GEMM, m97-style: global_load_lds staging + both-sides XOR swizzle.
template<typename CT>
__global__ __launch_bounds__(256)
void gemm_f16(const _Float16* __restrict__ A, int lda,
              const _Float16* __restrict__ BT,
              const float* __restrict__ bias,
              CT* __restrict__ C, int ldc, int K) {
  __shared__ _Float16 As[128][64];
  __shared__ _Float16 Bs[128][64];
  const int t = threadIdx.x;
  const int w = t >> 6, l = t & 63, lg = l >> 4, ll = l & 15;
  const int wr = w >> 1, wc = w & 1;
  const int m0 = blockIdx.y * 128, c0 = blockIdx.x * 128;

  const int srow = l >> 3;
  const int swz = ((l & 7) ^ (srow & 7)) * 8;
  const size_t aRow = (size_t)(m0 + w * 32 + srow);
  const size_t bRow = (size_t)(c0 + w * 32 + srow);

  f32x4 acc[4][4];
#pragma unroll
  for (int mf = 0; mf < 4; ++mf)
#pragma unroll
    for (int nf = 0; nf < 4; ++nf)
#pragma unroll
      for (int r = 0; r < 4; ++r) acc[mf][nf][r] = 0.f;

  for (int k0 = 0; k0 < K; k0 += 64) {
#pragma unroll
    for (int i = 0; i < 4; ++i) {
      int ldsOff = (w * 32 + i * 8) * 128 + l * 16;
      async_copy16((char*)As + ldsOff, A  + (aRow + i * 8) * lda + k0 + swz);
      async_copy16((char*)Bs + ldsOff, BT + (bRow + i * 8) * K   + k0 + swz);
    }
    __syncthreads();
#pragma unroll
    for (int ks = 0; ks < 2; ++ks) {
      f16x8 af[4], bf[4];
#pragma unroll
      for (int x = 0; x < 4; ++x) {
        int cA = ((ks * 4 + lg) ^ (ll & 7)) * 8;
        af[x] = *(const f16x8*)&As[wr * 64 + x * 16 + ll][cA];
        bf[x] = *(const f16x8*)&Bs[wc * 64 + x * 16 + ll][cA];
      }
#pragma unroll
      for (int mf = 0; mf < 4; ++mf)
#pragma unroll
        for (int nf = 0; nf < 4; ++nf)
          acc[mf][nf] = __builtin_amdgcn_mfma_f32_16x16x32_f16(af[mf], bf[nf], acc[mf][nf], 0, 0, 0);
    }
    __syncthreads();
  }
#pragma unroll
  for (int mf = 0; mf < 4; ++mf)
#pragma unroll
    for (int nf = 0; nf < 4; ++nf) {
      int col = c0 + wc * 64 + nf * 16 + ll;
      float bv = bias[col];
#pragma unroll
      for (int r = 0; r < 4; ++r) {
        int row = m0 + wr * 64 + mf * 16 + lg * 4 + r;
        C[(size_t)row * ldc + col] = (CT)(acc[mf][nf][r] + bv);
      }
    }
}

__global__ __launch_bounds__(256)
void rope_cvt(_Float16* __restrict__ qkv, const float* __restrict__ cosb,
              const float* __restrict__ sinb, const float* __restrict__ logn,
              _Float16* __restrict__ Kh) {
  int idx = blockIdx.x * 256 + threadIdx.x;
  int d = idx & 63;
  int h = (idx >> 6) & 15;
  int s = (idx >> 10) & 2047;
  int b = idx >> 21;
  size_t base = ((size_t)(b * Ssz + s)) * K3sz + h * HDsz;
  float c1 = cosb[s * HDsz + d];
  float s1 = sinb[s * HDsz + d];
  float c2 = cosb[s * HDsz + 64 + d];
  float s2 = sinb[s * HDsz + 64 + d];
  float ln = logn[s] * 0.08838834764831845f;
  float q1 = (float)qkv[base + d], q2 = (float)qkv[base + 64 + d];
  float k1 = (float)qkv[base + Hsz + d], k2 = (float)qkv[base + Hsz + 64 + d];
  qkv[base + d]      = (_Float16)((q1 * c1 - q2 * s1) * ln);
  qkv[base + 64 + d] = (_Float16)((q2 * c2 + q1 * s2) * ln);
  size_t ko = ((size_t)((b * NHsz + h) * Ssz + s)) * HDsz;
  Kh[ko + d]      = (_Float16)(k1 * c1 - k2 * s1);
  Kh[ko + 64 + d] = (_Float16)(k2 * c2 + k1 * s2);
}

__global__ __launch_bounds__(256)
void vtrans(const _Float16* __restrict__ qkv, _Float16* __restrict__ Vt) {
  __shared__ _Float16 T[128][72];
  const int t = threadIdx.x;
  const int s0 = blockIdx.x * 64;
  const int h = blockIdx.y;
  const int b = blockIdx.z;
#pragma unroll
  for (int i = 0; i < 4; ++i) {
    int c = i * 256 + t;
    int rr = c >> 4, c8 = c & 15;
    f16x8 v = *(const f16x8*)(qkv + ((size_t)(b * Ssz + s0 + rr)) * K3sz + 2 * Hsz + h * HDsz + c8 * 8);
#pragma unroll
    for (int j = 0; j < 8; ++j) T[c8 * 8 + j][rr] = v[j];
  }
  __syncthreads();
  _Float16* Vg = Vt + (size_t)(b * NHsz + h) * (Ssz * HDsz);
#pragma unroll
  for (int i = 0; i < 4; ++i) {
    int c = i * 256 + t;
    int d = c >> 3, s8 = c & 7;
    *(f16x8*)(Vg + (size_t)d * Ssz + s0 + s8 * 8) = *(const f16x8*)&T[d][s8 * 8];
  }
}

// fp16 MFMA causal flash attention v2: gload_lds + XOR swizzle, lane-partial
// lsum (deferred reduce), defer-max rescale (T13, THR=8).
__global__ __launch_bounds__(256)
void flash_mfma(_Float16* __restrict__ qkv, const _Float16* __restrict__ Kh,
                const _Float16* __restrict__ Vt) {
  __shared__ _Float16 Ks[64][128];
  __shared__ _Float16 Vs[128][64];
  __shared__ _Float16 Ps[4][16][64];
  const int t = threadIdx.x;
  const int w = t >> 6, l = t & 63, lg = l >> 4, ll = l & 15;
  const int qblk = 31 - (int)blockIdx.x;
  const int h = blockIdx.y, b = blockIdx.z;
  const size_t bh = (size_t)(b * NHsz + h);

  const int qrow_g = qblk * 64 + w * 16 + ll;
  f16x8 qf[4];
  {
    const _Float16* qrow = qkv + ((size_t)(b * Ssz) + qrow_g) * K3sz + h * HDsz;
#pragma unroll
    for (int kds = 0; kds < 4; ++kds)
      qf[kds] = *(const f16x8*)(qrow + kds * 32 + lg * 8);
  }

  f32x4 O[8];
#pragma unroll
  for (int nf = 0; nf < 8; ++nf)
#pragma unroll
    for (int r = 0; r < 4; ++r) O[nf][r] = 0.f;
  float m[4] = {-1e30f, -1e30f, -1e30f, -1e30f};
  float lp[4] = {0.f, 0.f, 0.f, 0.f};

  const _Float16* Kg = Kh + bh * (size_t)(Ssz * HDsz);
  const _Float16* Vg = Vt + bh * (size_t)(Ssz * HDsz);

  int kSrc[4], kLds[4], vSrc[4], vLds[4];
#pragma unroll
  for (int i = 0; i < 4; ++i) {
    int krow = w * 16 + i * 4 + (l >> 4);
    kSrc[i] = krow * 128 + (((l & 15) ^ (krow & 7)) * 8);
    kLds[i] = (w * 16 + i * 4) * 256 + l * 16;
    int vrow = w * 32 + i * 8 + (l >> 3);
    vSrc[i] = vrow * Ssz + (((l & 7) ^ (vrow & 7)) * 8);
    vLds[i] = (w * 32 + i * 8) * 128 + l * 16;
  }

  for (int kt = 0; kt <= qblk; ++kt) {
    const _Float16* Ktile = Kg + (size_t)kt * (64 * HDsz);
    const _Float16* Vtile = Vg + kt * 64;
#pragma unroll
    for (int i = 0; i < 4; ++i) {
      async_copy16((char*)Ks + kLds[i], Ktile + kSrc[i]);
      async_copy16((char*)Vs + vLds[i], Vtile + vSrc[i]);
    }
    __syncthreads();

    f32x4 S[4];
#pragma unroll
    for (int kf = 0; kf < 4; ++kf) {
#pragma unroll
      for (int r = 0; r < 4; ++r) S[kf][r] = 0.f;
#pragma unroll
      for (int kds = 0; kds < 4; ++kds) {
        f16x8 bk = *(const f16x8*)&Ks[kf * 16 + ll][(((kds * 4 + lg) ^ (ll & 7))) * 8];
        S[kf] = __builtin_amdgcn_mfma_f32_16x16x32_f16(qf[kds], bk, S[kf], 0, 0, 0);
      }
    }
    if (kt == qblk) {
#pragma unroll
      for (int kf = 0; kf < 4; ++kf) {
        int kcol = kt * 64 + kf * 16 + ll;
#pragma unroll
        for (int r = 0; r < 4; ++r) {
          int qg = qblk * 64 + w * 16 + lg * 4 + r;
          if (kcol > qg) S[kf][r] = -1e30f;
        }
      }
    }

    float pmax[4];
    bool need = false;
#pragma unroll
    for (int r = 0; r < 4; ++r) {
      float v = fmaxf(fmaxf(S[0][r], S[1][r]), fmaxf(S[2][r], S[3][r]));
      v = fmaxf(v, __shfl_xor(v, 1));
      v = fmaxf(v, __shfl_xor(v, 2));
      v = fmaxf(v, __shfl_xor(v, 4));
      v = fmaxf(v, __shfl_xor(v, 8));
      pmax[r] = v;
      need = need || (v > m[r] + 8.f);
    }
    if (__any(need)) {
#pragma unroll
      for (int r = 0; r < 4; ++r) {
        float mn = fmaxf(m[r], pmax[r]);
        float corr = __expf(m[r] - mn);
        lp[r] *= corr;
#pragma unroll
        for (int nf = 0; nf < 8; ++nf) O[nf][r] *= corr;
        m[r] = mn;
      }
    }
#pragma unroll
    for (int r = 0; r < 4; ++r) {
      int q7 = (lg * 4 + r) & 7;
      float p0 = __expf(S[0][r] - m[r]);
      float p1 = __expf(S[1][r] - m[r]);
      float p2 = __expf(S[2][r] - m[r]);
      float p3 = __expf(S[3][r] - m[r]);
      lp[r] += (p0 + p1) + (p2 + p3);
      int u = ll >> 3, s = ll & 7;
      Ps[w][lg * 4 + r][((0 + u) ^ q7) * 8 + s] = (_Float16)p0;
      Ps[w][lg * 4 + r][((2 + u) ^ q7) * 8 + s] = (_Float16)p1;
      Ps[w][lg * 4 + r][((4 + u) ^ q7) * 8 + s] = (_Float16)p2;
      Ps[w][lg * 4 + r][((6 + u) ^ q7) * 8 + s] = (_Float16)p3;
    }
    f16x8 pa0 = *(const f16x8*)&Ps[w][ll][((lg ^ (ll & 7))) * 8];
    f16x8 pa1 = *(const f16x8*)&Ps[w][ll][(((4 + lg) ^ (ll & 7))) * 8];
#pragma unroll
    for (int nf = 0; nf < 8; ++nf) {
      f16x8 vb0 = *(const f16x8*)&Vs[nf * 16 + ll][((lg ^ (ll & 7))) * 8];
      f16x8 vb1 = *(const f16x8*)&Vs[nf * 16 + ll][(((4 + lg) ^ (ll & 7))) * 8];
      O[nf] = __builtin_amdgcn_mfma_f32_16x16x32_f16(pa0, vb0, O[nf], 0, 0, 0);
      O[nf] = __builtin_amdgcn_mfma_f32_16x16x32_f16(pa1, vb1, O[nf], 0, 0, 0);
    }
    __syncthreads();
  }

#pragma unroll
  for (int r = 0; r < 4; ++r) {
    float s = lp[r];
    s += __shfl_xor(s, 1);
    s += __shfl_xor(s, 2);
    s += __shfl_xor(s, 4);
    s += __shfl_xor(s, 8);
    float inv = 1.f / s;
    _Float16* crow = qkv + ((size_t)(b * Ssz) + qblk * 64 + w * 16 + lg * 4 + r) * K3sz + h * HDsz;
#pragma unroll
    for (int nf = 0; nf < 8; ++nf)
      crow[nf * 16 + ll] = (_Float16)(O[nf][r] * inv);
  }
}

extern "C" void kernel_launch(void* const* d_in, const int* in_sizes, int n_in,
                              void* d_out, int out_size, void* d_ws, size_t ws_size,
                              hipStream_t stream) {
  const float* hs   = (const float*)d_in[0];
  const float* cosb = (const float*)d_in[1];
  const float* sinb = (const float*)d_in[2];
  // d_in[3] = attention_mask: pure causal, handled analytically
  const float* logn = (const float*)d_in[4];
  const float* Wc   = (const float*)d_in[5];
  const float* bc   = (const float*)d_in[6];
  const float* Wp   = (const float*)d_in[7];
  const float* bp   = (const float*)d_in[8];
  float* out = (float*)d_out;

  _Float16* qkv  = (_Float16*)d_ws;
  _Float16* hsF  = qkv  + (size_t)Msz * K3sz;
  _Float16* WcT  = hsF  + (size_t)Msz * Hsz;
  _Float16* WpT  = WcT  + (size_t)K3sz * Hsz;
  _Float16* Kh   = WpT  + (size_t)Hsz * Hsz;
  _Float16* Vt   = Kh   + (size_t)Bsz * NHsz * Ssz * HDsz;

  cvt_f32_f16<<<(Msz * Hsz) / (256 * 8), 256, 0, stream>>>(hs, hsF);
  { dim3 g(K3sz / 64, Hsz / 64); wtrans<<<g, 256, 0, stream>>>(Wc, WcT, K3sz, Hsz); }
  { dim3 g(Hsz / 64, Hsz / 64);  wtrans<<<g, 256, 0, stream>>>(Wp, WpT, Hsz, Hsz); }

  {
    dim3 g(K3sz / 128, Msz / 128);
    gemm_f16<_Float16><<<g, 256, 0, stream>>>(hsF, Hsz, WcT, bc, qkv, K3sz, Hsz);
  }
  rope_cvt<<<(Bsz * Ssz * NHsz * 64) / 256, 256, 0, stream>>>(qkv, cosb, sinb, logn, Kh);
  {
    dim3 g(Ssz / 64, NHsz, Bsz);
    vtrans<<<g, 256, 0, stream>>>(qkv, Vt);
  }
  {
    dim3 g(Ssz / 64, NHsz, Bsz);
    flash_mfma<<<g, 256, 0, stream>>>(qkv, Kh, Vt);
  }
  {
    dim3 g(Hsz / 128, Msz / 128);
    gemm_f16<float><<<g, 256, 0, stream>>>(qkv, K3sz, WpT, bp, out, Hsz, Hsz);
  }
}

// Round 7
// 448.312 us; speedup vs baseline: 11.4076x; 1.1060x over previous
//
#include <hip/hip_runtime.h>

#define Bsz 2
#define Ssz 2048
#define Hsz 2048
#define NHsz 16
#define HDsz 128
#define K3sz 6144
#define Msz 4096

typedef _Float16 f16x8 __attribute__((ext_vector_type(8)));
typedef float f32x4 __attribute__((ext_vector_type(4)));

typedef __attribute__((address_space(3))) void lds_void;
typedef __attribute__((address_space(1))) void glob_void;
__device__ __forceinline__ void async_copy16(void* lds, const void* g) {
  __builtin_amdgcn_global_load_lds((const glob_void*)g, (lds_void*)lds, 16, 0, 0);
}

__global__ __launch_bounds__(256)
void cvt_f32_f16(const float* __restrict__ in, _Float16* __restrict__ out) {
  size_t i = ((size_t)blockIdx.x * 256 + threadIdx.x) * 8;
  float4 a = *(const float4*)(in + i);
  float4 b = *(const float4*)(in + i + 4);
  f16x8 v;
  v[0] = (_Float16)a.x; v[1] = (_Float16)a.y; v[2] = (_Float16)a.z; v[3] = (_Float16)a.w;
  v[4] = (_Float16)b.x; v[5] = (_Float16)b.y; v[6] = (_Float16)b.z; v[7] = (_Float16)b.w;
  *(f16x8*)(out + i) = v;
}

__global__ __launch_bounds__(256)
void wtrans(const float* __restrict__ W, _Float16* __restrict__ WT, int N, int K) {
  __shared__ _Float16 T[64][72];
  const int t = threadIdx.x;
  const int n0 = blockIdx.x * 64, k0 = blockIdx.y * 64;
#pragma unroll
  for (int i = 0; i < 4; ++i) {
    int c = i * 256 + t;
    int rr = c >> 4, c4 = c & 15;
    float4 v = *(const float4*)(W + (size_t)(k0 + rr) * N + n0 + c4 * 4);
    T[c4 * 4 + 0][rr] = (_Float16)v.x;
    T[c4 * 4 + 1][rr] = (_Float16)v.y;
    T[c4 * 4 + 2][rr] = (_Float16)v.z;
    T[c4 * 4 + 3][rr] = (_Float16)v.w;
  }
  __syncthreads();
#pragma unroll
  for (int i = 0; i < 2; ++i) {
    int c = i * 256 + t;
    int nn = c >> 3, k8 = c & 7;
    *(f16x8*)(WT + (size_t)(n0 + nn) * K + k0 + k8 * 8) = *(const f16x8*)&T[nn][k8 * 8];
  }
}

// fp16 MFMA GEMM (unchanged from round 6): gload_lds + both-sides XOR swizzle.
template<typename CT>
__global__ __launch_bounds__(256)
void gemm_f16(const _Float16* __restrict__ A, int lda,
              const _Float16* __restrict__ BT,
              const float* __restrict__ bias,
              CT* __restrict__ C, int ldc, int K) {
  __shared__ _Float16 As[128][64];
  __shared__ _Float16 Bs[128][64];
  const int t = threadIdx.x;
  const int w = t >> 6, l = t & 63, lg = l >> 4, ll = l & 15;
  const int wr = w >> 1, wc = w & 1;
  const int m0 = blockIdx.y * 128, c0 = blockIdx.x * 128;

  const int srow = l >> 3;
  const int swz = ((l & 7) ^ (srow & 7)) * 8;
  const size_t aRow = (size_t)(m0 + w * 32 + srow);
  const size_t bRow = (size_t)(c0 + w * 32 + srow);

  f32x4 acc[4][4];
#pragma unroll
  for (int mf = 0; mf < 4; ++mf)
#pragma unroll
    for (int nf = 0; nf < 4; ++nf)
#pragma unroll
      for (int r = 0; r < 4; ++r) acc[mf][nf][r] = 0.f;

  for (int k0 = 0; k0 < K; k0 += 64) {
#pragma unroll
    for (int i = 0; i < 4; ++i) {
      int ldsOff = (w * 32 + i * 8) * 128 + l * 16;
      async_copy16((char*)As + ldsOff, A  + (aRow + i * 8) * lda + k0 + swz);
      async_copy16((char*)Bs + ldsOff, BT + (bRow + i * 8) * K   + k0 + swz);
    }
    __syncthreads();
#pragma unroll
    for (int ks = 0; ks < 2; ++ks) {
      f16x8 af[4], bf[4];
#pragma unroll
      for (int x = 0; x < 4; ++x) {
        int cA = ((ks * 4 + lg) ^ (ll & 7)) * 8;
        af[x] = *(const f16x8*)&As[wr * 64 + x * 16 + ll][cA];
        bf[x] = *(const f16x8*)&Bs[wc * 64 + x * 16 + ll][cA];
      }
#pragma unroll
      for (int mf = 0; mf < 4; ++mf)
#pragma unroll
        for (int nf = 0; nf < 4; ++nf)
          acc[mf][nf] = __builtin_amdgcn_mfma_f32_16x16x32_f16(af[mf], bf[nf], acc[mf][nf], 0, 0, 0);
    }
    __syncthreads();
  }
#pragma unroll
  for (int mf = 0; mf < 4; ++mf)
#pragma unroll
    for (int nf = 0; nf < 4; ++nf) {
      int col = c0 + wc * 64 + nf * 16 + ll;
      float bv = bias[col];
#pragma unroll
      for (int r = 0; r < 4; ++r) {
        int row = m0 + wr * 64 + mf * 16 + lg * 4 + r;
        C[(size_t)row * ldc + col] = (CT)(acc[mf][nf][r] + bv);
      }
    }
}

__global__ __launch_bounds__(256)
void rope_cvt(_Float16* __restrict__ qkv, const float* __restrict__ cosb,
              const float* __restrict__ sinb, const float* __restrict__ logn,
              _Float16* __restrict__ Kh) {
  int idx = blockIdx.x * 256 + threadIdx.x;
  int d = idx & 63;
  int h = (idx >> 6) & 15;
  int s = (idx >> 10) & 2047;
  int b = idx >> 21;
  size_t base = ((size_t)(b * Ssz + s)) * K3sz + h * HDsz;
  float c1 = cosb[s * HDsz + d];
  float s1 = sinb[s * HDsz + d];
  float c2 = cosb[s * HDsz + 64 + d];
  float s2 = sinb[s * HDsz + 64 + d];
  float ln = logn[s] * 0.08838834764831845f;
  float q1 = (float)qkv[base + d], q2 = (float)qkv[base + 64 + d];
  float k1 = (float)qkv[base + Hsz + d], k2 = (float)qkv[base + Hsz + 64 + d];
  qkv[base + d]      = (_Float16)((q1 * c1 - q2 * s1) * ln);
  qkv[base + 64 + d] = (_Float16)((q2 * c2 + q1 * s2) * ln);
  size_t ko = ((size_t)((b * NHsz + h) * Ssz + s)) * HDsz;
  Kh[ko + d]      = (_Float16)(k1 * c1 - k2 * s1);
  Kh[ko + 64 + d] = (_Float16)(k2 * c2 + k1 * s2);
}

__global__ __launch_bounds__(256)
void vtrans(const _Float16* __restrict__ qkv, _Float16* __restrict__ Vt) {
  __shared__ _Float16 T[128][72];
  const int t = threadIdx.x;
  const int s0 = blockIdx.x * 64;
  const int h = blockIdx.y;
  const int b = blockIdx.z;
#pragma unroll
  for (int i = 0; i < 4; ++i) {
    int c = i * 256 + t;
    int rr = c >> 4, c8 = c & 15;
    f16x8 v = *(const f16x8*)(qkv + ((size_t)(b * Ssz + s0 + rr)) * K3sz + 2 * Hsz + h * HDsz + c8 * 8);
#pragma unroll
    for (int j = 0; j < 8; ++j) T[c8 * 8 + j][rr] = v[j];
  }
  __syncthreads();
  _Float16* Vg = Vt + (size_t)(b * NHsz + h) * (Ssz * HDsz);
#pragma unroll
  for (int i = 0; i < 4; ++i) {
    int c = i * 256 + t;
    int d = c >> 3, s8 = c & 7;
    *(f16x8*)(Vg + (size_t)d * Ssz + s0 + s8 * 8) = *(const f16x8*)&T[d][s8 * 8];
  }
}

// flash v3: QBLK=128 (2 row-groups/wave, K/V frag reuse x2), 2-phase double
// buffer with counted vmcnt(8) (loads in flight across raw s_barrier),
// grid x=h for XCD L2 locality, b-flip qblk mapping for per-CU balance.
__global__ __launch_bounds__(256)
void flash_mfma(_Float16* __restrict__ qkv, const _Float16* __restrict__ Kh,
                const _Float16* __restrict__ Vt) {
  __shared__ _Float16 Ks[2][64][128];
  __shared__ _Float16 Vs[2][128][64];
  __shared__ _Float16 Ps[4][2][16][64];
  const int t = threadIdx.x;
  const int w = t >> 6, l = t & 63, lg = l >> 4, ll = l & 15;
  const int h = blockIdx.x;                       // same-h blocks: flat-id stride 16 -> same XCD
  const int qblk = (blockIdx.z == 0) ? (int)blockIdx.y : (15 - (int)blockIdx.y);
  const int b = blockIdx.z;
  const size_t bh = (size_t)(b * NHsz + h);

  // Q fragments: 2 row-groups of 16
  f16x8 qf[2][4];
#pragma unroll
  for (int mg = 0; mg < 2; ++mg) {
    const _Float16* qrow = qkv + ((size_t)(b * Ssz) + qblk * 128 + w * 32 + mg * 16 + ll) * K3sz + h * HDsz;
#pragma unroll
    for (int kds = 0; kds < 4; ++kds)
      qf[mg][kds] = *(const f16x8*)(qrow + kds * 32 + lg * 8);
  }

  f32x4 O[2][8];
#pragma unroll
  for (int mg = 0; mg < 2; ++mg)
#pragma unroll
    for (int nf = 0; nf < 8; ++nf)
#pragma unroll
      for (int r = 0; r < 4; ++r) O[mg][nf][r] = 0.f;
  float m[2][4], lp[2][4];
#pragma unroll
  for (int mg = 0; mg < 2; ++mg)
#pragma unroll
    for (int r = 0; r < 4; ++r) { m[mg][r] = -1e30f; lp[mg][r] = 0.f; }

  const _Float16* Kg = Kh + bh * (size_t)(Ssz * HDsz);
  const _Float16* Vg = Vt + bh * (size_t)(Ssz * HDsz);

  int kSrc[4], kLds[4], vSrc[4], vLds[4];
#pragma unroll
  for (int i = 0; i < 4; ++i) {
    int krow = w * 16 + i * 4 + (l >> 4);
    kSrc[i] = krow * 128 + (((l & 15) ^ (krow & 7)) * 8);
    kLds[i] = (w * 16 + i * 4) * 256 + l * 16;
    int vrow = w * 32 + i * 8 + (l >> 3);
    vSrc[i] = vrow * Ssz + (((l & 7) ^ (vrow & 7)) * 8);
    vLds[i] = (w * 32 + i * 8) * 128 + l * 16;
  }

  const int nt = 2 * qblk + 2;
  // prologue: stage tile 0 into buffer 0
#pragma unroll
  for (int i = 0; i < 4; ++i) {
    async_copy16((char*)Ks[0] + kLds[i], Kg + kSrc[i]);
    async_copy16((char*)Vs[0] + vLds[i], Vg + vSrc[i]);
  }
  int cb = 0;

  for (int kt = 0; kt < nt; ++kt) {
    if (kt + 1 < nt) {
      const _Float16* Ktile = Kg + (size_t)(kt + 1) * (64 * HDsz);
      const _Float16* Vtile = Vg + (kt + 1) * 64;
#pragma unroll
      for (int i = 0; i < 4; ++i) {
        async_copy16((char*)Ks[cb ^ 1] + kLds[i], Ktile + kSrc[i]);
        async_copy16((char*)Vs[cb ^ 1] + vLds[i], Vtile + vSrc[i]);
      }
      asm volatile("s_waitcnt vmcnt(8)" ::: "memory");  // tile kt resident; kt+1 in flight
    } else {
      asm volatile("s_waitcnt vmcnt(0)" ::: "memory");
    }
    __builtin_amdgcn_sched_barrier(0);
    __builtin_amdgcn_s_barrier();
    __builtin_amdgcn_sched_barrier(0);

    // QK^T both row-groups; each K-fragment feeds 2 MFMAs
    f32x4 S[2][4];
#pragma unroll
    for (int mg = 0; mg < 2; ++mg)
#pragma unroll
      for (int kf = 0; kf < 4; ++kf)
#pragma unroll
        for (int r = 0; r < 4; ++r) S[mg][kf][r] = 0.f;
#pragma unroll
    for (int kf = 0; kf < 4; ++kf)
#pragma unroll
      for (int kds = 0; kds < 4; ++kds) {
        f16x8 bk = *(const f16x8*)&Ks[cb][kf * 16 + ll][(((kds * 4 + lg) ^ (ll & 7))) * 8];
        S[0][kf] = __builtin_amdgcn_mfma_f32_16x16x32_f16(qf[0][kds], bk, S[0][kf], 0, 0, 0);
        S[1][kf] = __builtin_amdgcn_mfma_f32_16x16x32_f16(qf[1][kds], bk, S[1][kf], 0, 0, 0);
      }
    if (kt >= 2 * qblk) {  // diagonal tiles only
#pragma unroll
      for (int mg = 0; mg < 2; ++mg)
#pragma unroll
        for (int kf = 0; kf < 4; ++kf) {
          int kcol = kt * 64 + kf * 16 + ll;
#pragma unroll
          for (int r = 0; r < 4; ++r) {
            int qg = qblk * 128 + w * 32 + mg * 16 + lg * 4 + r;
            if (kcol > qg) S[mg][kf][r] = -1e30f;
          }
        }
    }

    // defer-max online softmax (T13, THR=8)
    float pmax[2][4];
    bool need = false;
#pragma unroll
    for (int mg = 0; mg < 2; ++mg)
#pragma unroll
      for (int r = 0; r < 4; ++r) {
        float v = fmaxf(fmaxf(S[mg][0][r], S[mg][1][r]), fmaxf(S[mg][2][r], S[mg][3][r]));
        v = fmaxf(v, __shfl_xor(v, 1));
        v = fmaxf(v, __shfl_xor(v, 2));
        v = fmaxf(v, __shfl_xor(v, 4));
        v = fmaxf(v, __shfl_xor(v, 8));
        pmax[mg][r] = v;
        need = need || (v > m[mg][r] + 8.f);
      }
    if (__any(need)) {
#pragma unroll
      for (int mg = 0; mg < 2; ++mg)
#pragma unroll
        for (int r = 0; r < 4; ++r) {
          float mn = fmaxf(m[mg][r], pmax[mg][r]);
          float corr = __expf(m[mg][r] - mn);
          lp[mg][r] *= corr;
#pragma unroll
          for (int nf = 0; nf < 8; ++nf) O[mg][nf][r] *= corr;
          m[mg][r] = mn;
        }
    }
#pragma unroll
    for (int mg = 0; mg < 2; ++mg)
#pragma unroll
      for (int r = 0; r < 4; ++r) {
        int q7 = (lg * 4 + r) & 7;
        float p0 = __expf(S[mg][0][r] - m[mg][r]);
        float p1 = __expf(S[mg][1][r] - m[mg][r]);
        float p2 = __expf(S[mg][2][r] - m[mg][r]);
        float p3 = __expf(S[mg][3][r] - m[mg][r]);
        lp[mg][r] += (p0 + p1) + (p2 + p3);
        int u = ll >> 3, s = ll & 7;
        Ps[w][mg][lg * 4 + r][((0 + u) ^ q7) * 8 + s] = (_Float16)p0;
        Ps[w][mg][lg * 4 + r][((2 + u) ^ q7) * 8 + s] = (_Float16)p1;
        Ps[w][mg][lg * 4 + r][((4 + u) ^ q7) * 8 + s] = (_Float16)p2;
        Ps[w][mg][lg * 4 + r][((6 + u) ^ q7) * 8 + s] = (_Float16)p3;
      }
    // PV: each V-fragment feeds 2 MFMAs
    f16x8 pa[2][2];
#pragma unroll
    for (int mg = 0; mg < 2; ++mg) {
      pa[mg][0] = *(const f16x8*)&Ps[w][mg][ll][((lg ^ (ll & 7))) * 8];
      pa[mg][1] = *(const f16x8*)&Ps[w][mg][ll][(((4 + lg) ^ (ll & 7))) * 8];
    }
#pragma unroll
    for (int nf = 0; nf < 8; ++nf) {
      f16x8 vb0 = *(const f16x8*)&Vs[cb][nf * 16 + ll][((lg ^ (ll & 7))) * 8];
      f16x8 vb1 = *(const f16x8*)&Vs[cb][nf * 16 + ll][(((4 + lg) ^ (ll & 7))) * 8];
      O[0][nf] = __builtin_amdgcn_mfma_f32_16x16x32_f16(pa[0][0], vb0, O[0][nf], 0, 0, 0);
      O[0][nf] = __builtin_amdgcn_mfma_f32_16x16x32_f16(pa[0][1], vb1, O[0][nf], 0, 0, 0);
      O[1][nf] = __builtin_amdgcn_mfma_f32_16x16x32_f16(pa[1][0], vb0, O[1][nf], 0, 0, 0);
      O[1][nf] = __builtin_amdgcn_mfma_f32_16x16x32_f16(pa[1][1], vb1, O[1][nf], 0, 0, 0);
    }
    __builtin_amdgcn_sched_barrier(0);
    __builtin_amdgcn_s_barrier();   // all reads of cb done before next stage overwrites it
    cb ^= 1;
  }

  // epilogue: deferred lsum reduce + fp16 ctx into qkv q-region (own rows)
#pragma unroll
  for (int mg = 0; mg < 2; ++mg)
#pragma unroll
    for (int r = 0; r < 4; ++r) {
      float s = lp[mg][r];
      s += __shfl_xor(s, 1);
      s += __shfl_xor(s, 2);
      s += __shfl_xor(s, 4);
      s += __shfl_xor(s, 8);
      float inv = 1.f / s;
      _Float16* crow = qkv + ((size_t)(b * Ssz) + qblk * 128 + w * 32 + mg * 16 + lg * 4 + r) * K3sz + h * HDsz;
#pragma unroll
      for (int nf = 0; nf < 8; ++nf)
        crow[nf * 16 + ll] = (_Float16)(O[mg][nf][r] * inv);
    }
}

extern "C" void kernel_launch(void* const* d_in, const int* in_sizes, int n_in,
                              void* d_out, int out_size, void* d_ws, size_t ws_size,
                              hipStream_t stream) {
  const float* hs   = (const float*)d_in[0];
  const float* cosb = (const float*)d_in[1];
  const float* sinb = (const float*)d_in[2];
  // d_in[3] = attention_mask: pure causal, handled analytically
  const float* logn = (const float*)d_in[4];
  const float* Wc   = (const float*)d_in[5];
  const float* bc   = (const float*)d_in[6];
  const float* Wp   = (const float*)d_in[7];
  const float* bp   = (const float*)d_in[8];
  float* out = (float*)d_out;

  _Float16* qkv  = (_Float16*)d_ws;
  _Float16* hsF  = qkv  + (size_t)Msz * K3sz;
  _Float16* WcT  = hsF  + (size_t)Msz * Hsz;
  _Float16* WpT  = WcT  + (size_t)K3sz * Hsz;
  _Float16* Kh   = WpT  + (size_t)Hsz * Hsz;
  _Float16* Vt   = Kh   + (size_t)Bsz * NHsz * Ssz * HDsz;

  cvt_f32_f16<<<(Msz * Hsz) / (256 * 8), 256, 0, stream>>>(hs, hsF);
  { dim3 g(K3sz / 64, Hsz / 64); wtrans<<<g, 256, 0, stream>>>(Wc, WcT, K3sz, Hsz); }
  { dim3 g(Hsz / 64, Hsz / 64);  wtrans<<<g, 256, 0, stream>>>(Wp, WpT, Hsz, Hsz); }

  {
    dim3 g(K3sz / 128, Msz / 128);
    gemm_f16<_Float16><<<g, 256, 0, stream>>>(hsF, Hsz, WcT, bc, qkv, K3sz, Hsz);
  }
  rope_cvt<<<(Bsz * Ssz * NHsz * 64) / 256, 256, 0, stream>>>(qkv, cosb, sinb, logn, Kh);
  {
    dim3 g(Ssz / 64, NHsz, Bsz);
    vtrans<<<g, 256, 0, stream>>>(qkv, Vt);
  }
  {
    dim3 g(NHsz, Ssz / 128, Bsz);   // x=h: XCD L2 locality for K/V panels
    flash_mfma<<<g, 256, 0, stream>>>(qkv, Kh, Vt);
  }
  {
    dim3 g(Hsz / 128, Msz / 128);
    gemm_f16<float><<<g, 256, 0, stream>>>(qkv, K3sz, WpT, bp, out, Hsz, Hsz);
  }
}